// Round 1
// baseline (430.860 us; speedup 1.0000x reference)
//
#include <hip/hip_runtime.h>
#include <hip/hip_fp16.h>
#include <stdint.h>

#define LOG2E 1.4426950408889634f
#define LN2   0.6931471805599453f

// ---------- scalar trans helpers ----------
__device__ __forceinline__ float fast_softplus(float x) {
    float ax = fabsf(x);
    float t = LN2 * __builtin_amdgcn_logf(1.0f + __builtin_amdgcn_exp2f(-LOG2E * ax));
    return fmaxf(x, 0.0f) + t;
}
__device__ __forceinline__ float fast_ln(float x) {
    return LN2 * __builtin_amdgcn_logf(x);
}
__device__ __forceinline__ float fast_tanh(float x) {
    // tanh(x) = 1 - 2/(exp(2x)+1); trans-pipe version (used only in f2: 16/row)
    float e = __builtin_amdgcn_exp2f(x * (2.0f * LOG2E));
    return 1.0f - 2.0f * __builtin_amdgcn_rcpf(e + 1.0f);
}

// uniform load pinned to SGPR (returns raw bits)
__device__ __forceinline__ unsigned int uload_bits(const float* __restrict__ p) {
    return (unsigned int)__builtin_amdgcn_readfirstlane(__float_as_int(*p));
}
__device__ __forceinline__ float uload(const float* __restrict__ p) {
    return __int_as_float(__builtin_amdgcn_readfirstlane(__float_as_int(*p)));
}

// ---------- packed f16 tanh: normalized Pade(5,6), no clamp (|x|<=3.7 by construction),
// magic-seed reciprocal + 1 Newton. ~11 VOP3P instructions, no trans. ----------
__device__ __forceinline__ __half2 pk_tanh(__half2 x) {
    const __half2 ONE = __float2half2_rn(1.0f);
    __half2 t   = __hmul2(x, x);                                     // t = x^2, t <= ~13.5
    __half2 num = __hfma2(t, __float2half2_rn(0.00202020f),
                             __float2half2_rn(0.12121212f));
    num = __hfma2(t, num, ONE);
    num = __hmul2(num, x);
    __half2 den = __hfma2(t, __float2half2_rn(9.62001e-5f),
                             __float2half2_rn(0.02020202f));
    den = __hfma2(t, den, __float2half2_rn(0.45454545f));
    den = __hfma2(t, den, ONE);                                      // den in [1, ~11.1]
    // per-half magic rcp seed: den bits <= 0x4990 < 0x7799 -> no cross-half borrow
    unsigned int du = __builtin_bit_cast(unsigned int, den);
    __half2 r = __builtin_bit_cast(__half2, 0x77997799u - du);       // ~5% err
    r = __hfma2(r, __hfma2(__hneg2(den), r, ONE), r);                // Newton -> ~0.2%
    return __hmul2(num, r);
}

// ---------- weight prep ----------
// ws layout (floats):
//   [0..71]    f1_W dup-packed half2      [72..79]   f1_b dup-packed half2
//   [80..143]  f2_0_W f32                 [144..151] f2_0_b f32
//   [152..159] sp(f2tau_W)                [160..167] sp(f2tau_b)
//   [168..231] sp(f2_1_W)                 [232..239] sp(f2_1_b)
//   [240..247] sp(f2_2_W)                 [248]      sp(f2_2_b)
__global__ void prep_kernel(
    const float* __restrict__ f1W,  const float* __restrict__ f1b,
    const float* __restrict__ f2tW, const float* __restrict__ f2tb,
    const float* __restrict__ f20W, const float* __restrict__ f20b,
    const float* __restrict__ f21W, const float* __restrict__ f21b,
    const float* __restrict__ f22W, const float* __restrict__ f22b,
    float* __restrict__ w)
{
    int t = threadIdx.x;
    if (t < 72) {
        __half2 h = __float2half2_rn(f1W[t]);
        w[t] = __builtin_bit_cast(float, h);
    }
    if (t < 8) {
        __half2 h = __float2half2_rn(f1b[t]);
        w[72 + t] = __builtin_bit_cast(float, h);
    }
    if (t < 64) w[80 + t]   = f20W[t];
    if (t < 8)  w[144 + t]  = f20b[t];
    if (t < 8)  w[152 + t]  = fast_softplus(f2tW[t]);
    if (t < 8)  w[160 + t]  = fast_softplus(f2tb[t]);
    if (t < 64) w[168 + t]  = fast_softplus(f21W[t]);
    if (t < 8)  w[232 + t]  = fast_softplus(f21b[t]);
    if (t < 8)  w[240 + t]  = fast_softplus(f22W[t]);
    if (t == 0) w[248]      = fast_softplus(f22b[0]);
}

// f32 f2 head (high-gain layers stay f32; tanh on trans pipe): flow[8] -> hazard
__device__ __forceinline__ float f2_head(const float* __restrict__ w,
                                         const float fl[8], float tv) {
    float h[8];
    #pragma unroll
    for (int o = 0; o < 8; ++o) {
        float acc = uload(w + 144 + o) + tv * uload(w + 152 + o) + uload(w + 160 + o);
        #pragma unroll
        for (int k = 0; k < 8; ++k) acc = fmaf(uload(w + 80 + o * 8 + k), fl[k], acc);
        h[o] = fast_tanh(acc);
    }
    float g[8];
    #pragma unroll
    for (int o = 0; o < 8; ++o) {
        float acc = uload(w + 232 + o);
        #pragma unroll
        for (int k = 0; k < 8; ++k) acc = fmaf(uload(w + 168 + o * 8 + k), h[k], acc);
        g[o] = fast_tanh(acc);
    }
    float z = uload(w + 248);
    #pragma unroll
    for (int k = 0; k < 8; ++k) z = fmaf(uload(w + 240 + k), g[k], z);
    return fast_softplus(z);
}

// ---------- main kernel: one thread per TWO rows, f1 recurrence in v_pk_*_f16 ----------
__global__ void __launch_bounds__(256) haz_kernel(
    const float* __restrict__ Y,
    const float* __restrict__ tau,
    const float* __restrict__ w,
    float* __restrict__ out,
    int npairs, int n)
{
    int i = blockIdx.x * blockDim.x + threadIdx.x;
    if (i >= npairs) return;
    int r0 = 2 * i;
    bool has1 = (r0 + 1) < n;
    int r1 = has1 ? r0 + 1 : r0;

    // tau prefetch: issue the coalesced 8B load FIRST so its ~L2/HBM latency
    // hides under the entire f1 recurrence (it was previously issued right
    // before its use in f2_head — a dependent tail stall).
    float tv0, tv1;
    if (has1) {
        float2 t2 = ((const float2*)tau)[i];
        tv0 = t2.x; tv1 = t2.y;
    } else {
        tv0 = tau[r0]; tv1 = tv0;          // avoid 4B OOB read on odd tail
    }

    union R { float4 v[4]; float s[16]; };
    R A, B;
    const float4* ya = (const float4*)(Y + (size_t)r0 * 16);
    const float4* yb = (const float4*)(Y + (size_t)r1 * 16);
    A.v[0] = ya[0]; A.v[1] = ya[1]; A.v[2] = ya[2]; A.v[3] = ya[3];
    B.v[0] = yb[0]; B.v[1] = yb[1]; B.v[2] = yb[2]; B.v[3] = yb[3];

    // yd[t] = log(diff+0.1) computed in f32 (trans pipe), packed (rowA, rowB)
    __half2 yd[11];
    #pragma unroll
    for (int j = 0; j < 11; ++j) {
        float da = fast_ln(A.s[4 + j] - A.s[3 + j] + 0.1f);
        float db = fast_ln(B.s[4 + j] - B.s[3 + j] + 0.1f);
        yd[j] = __halves2half2(__float2half(da), __float2half(db));
    }

    // f1 weights: dup-packed half2 bits pinned to SGPRs
    unsigned int Wk[72], Bk[8];
    #pragma unroll
    for (int k = 0; k < 72; ++k) Wk[k] = uload_bits(w + k);
    #pragma unroll
    for (int k = 0; k < 8; ++k)  Bk[k] = uload_bits(w + 72 + k);

    // recurrent f1: 11 steps of tanh(Linear(9->8)), both rows packed in half2
    __half2 flow[8];
    #pragma unroll
    for (int k = 0; k < 8; ++k) flow[k] = __float2half2_rn(0.0f);

    #pragma unroll
    for (int t = 0; t < 11; ++t) {
        __half2 nf[8];
        #pragma unroll
        for (int o = 0; o < 8; ++o) {
            __half2 acc = __builtin_bit_cast(__half2, Bk[o]);
            #pragma unroll
            for (int k = 0; k < 8; ++k)
                acc = __hfma2(__builtin_bit_cast(__half2, Wk[o * 9 + k]), flow[k], acc);
            acc = __hfma2(__builtin_bit_cast(__half2, Wk[o * 9 + 8]), yd[t], acc);
            nf[o] = pk_tanh(acc);
        }
        #pragma unroll
        for (int o = 0; o < 8; ++o) flow[o] = nf[o];
    }

    // unpack to f32; run the high-gain f2 head per row in f32
    float flA[8], flB[8];
    #pragma unroll
    for (int k = 0; k < 8; ++k) {
        flA[k] = __low2float(flow[k]);
        flB[k] = __high2float(flow[k]);
    }

    float o0 = f2_head(w, flA, tv0);
    float o1 = f2_head(w, flB, tv1);

    if (has1) {
        ((float2*)out)[i] = make_float2(o0, o1);
    } else {
        out[r0] = o0;
    }
}

extern "C" void kernel_launch(void* const* d_in, const int* in_sizes, int n_in,
                              void* d_out, int out_size, void* d_ws, size_t ws_size,
                              hipStream_t stream)
{
    const float* Y   = (const float*)d_in[0];
    const float* tau = (const float*)d_in[1];
    float* w = (float*)d_ws;
    float* out = (float*)d_out;
    int n = in_sizes[1];
    int npairs = (n + 1) / 2;

    prep_kernel<<<1, 128, 0, stream>>>(
        (const float*)d_in[2],  (const float*)d_in[3],
        (const float*)d_in[4],  (const float*)d_in[5],
        (const float*)d_in[6],  (const float*)d_in[7],
        (const float*)d_in[8],  (const float*)d_in[9],
        (const float*)d_in[10], (const float*)d_in[11],
        w);

    haz_kernel<<<(npairs + 255) / 256, 256, 0, stream>>>(Y, tau, w, out, npairs, n);
}

// Round 2
// 429.891 us; speedup vs baseline: 1.0023x; 1.0023x over previous
//
#include <hip/hip_runtime.h>
#include <hip/hip_fp16.h>
#include <stdint.h>

#define LOG2E 1.4426950408889634f
#define LN2   0.6931471805599453f

// ---------- scalar trans helpers ----------
__device__ __forceinline__ float fast_softplus(float x) {
    float ax = fabsf(x);
    float t = LN2 * __builtin_amdgcn_logf(1.0f + __builtin_amdgcn_exp2f(-LOG2E * ax));
    return fmaxf(x, 0.0f) + t;
}
__device__ __forceinline__ float fast_ln(float x) {
    return LN2 * __builtin_amdgcn_logf(x);
}
__device__ __forceinline__ float fast_tanh(float x) {
    // tanh(x) = 1 - 2/(exp(2x)+1); trans-pipe version (used only in f2: 16/row)
    float e = __builtin_amdgcn_exp2f(x * (2.0f * LOG2E));
    return 1.0f - 2.0f * __builtin_amdgcn_rcpf(e + 1.0f);
}

// uniform load pinned to SGPR (returns raw bits)
__device__ __forceinline__ unsigned int uload_bits(const float* __restrict__ p) {
    return (unsigned int)__builtin_amdgcn_readfirstlane(__float_as_int(*p));
}
__device__ __forceinline__ float uload(const float* __restrict__ p) {
    return __int_as_float(__builtin_amdgcn_readfirstlane(__float_as_int(*p)));
}

// ---------- pk_tanh constants, held in VGPRs for the whole kernel ----------
// dup-packed f16 pairs of the Pade(5,6) coefficients (same values as before)
struct TanhC {
    unsigned a1, a2, b1, b2, b3, one;
};

// ---------- packed f16 tanh: guaranteed 11 VOP3P instructions via inline asm.
// Same normalized Pade(5,6) + magic-seed rcp + 1 Newton as the intrinsic
// version; constants passed in VGPRs (VOP3P forbids literals), neg via
// neg_lo/neg_hi modifiers. ----------
__device__ __forceinline__ __half2 pk_tanh(__half2 xh, const TanhC& c) {
    unsigned x = __builtin_bit_cast(unsigned, xh);
    unsigned o, t, n, d, r, e;
    asm("v_pk_mul_f16 %1, %6, %6\n\t"                                   // t = x*x
        "v_pk_fma_f16 %2, %1, %8, %7\n\t"                               // n = a2*t + a1
        "v_pk_fma_f16 %2, %1, %2, %12\n\t"                              // n = n*t + 1
        "v_pk_mul_f16 %2, %2, %6\n\t"                                   // n *= x
        "v_pk_fma_f16 %3, %1, %11, %10\n\t"                             // d = b3*t + b2
        "v_pk_fma_f16 %3, %1, %3, %9\n\t"                               // d = d*t + b1
        "v_pk_fma_f16 %3, %1, %3, %12\n\t"                              // d = d*t + 1
        "v_sub_u32    %4, 0x77997799, %3\n\t"                           // magic rcp seed
        "v_pk_fma_f16 %5, %4, %3, %12 neg_lo:[0,1,0] neg_hi:[0,1,0]\n\t"// e = 1 - r*d
        "v_pk_fma_f16 %4, %4, %5, %4\n\t"                               // r = r*e + r
        "v_pk_mul_f16 %0, %2, %4"                                       // o = n*r
        : "=v"(o), "=&v"(t), "=&v"(n), "=&v"(d), "=&v"(r), "=&v"(e)
        : "v"(x), "v"(c.a1), "v"(c.a2), "v"(c.b1), "v"(c.b2), "v"(c.b3),
          "v"(c.one));
    return __builtin_bit_cast(__half2, o);
}

// ---------- weight prep ----------
// ws layout (floats):
//   [0..71]    f1_W dup-packed half2      [72..79]   f1_b dup-packed half2
//   [80..143]  f2_0_W f32                 [144..151] f2_0_b + sp(f2tau_b) f32
//   [152..159] sp(f2tau_W)                [160..167] sp(f2tau_b) (unused)
//   [168..231] sp(f2_1_W)                 [232..239] sp(f2_1_b)
//   [240..247] sp(f2_2_W)                 [248]      sp(f2_2_b)
__global__ void prep_kernel(
    const float* __restrict__ f1W,  const float* __restrict__ f1b,
    const float* __restrict__ f2tW, const float* __restrict__ f2tb,
    const float* __restrict__ f20W, const float* __restrict__ f20b,
    const float* __restrict__ f21W, const float* __restrict__ f21b,
    const float* __restrict__ f22W, const float* __restrict__ f22b,
    float* __restrict__ w)
{
    int t = threadIdx.x;
    if (t < 72) {
        __half2 h = __float2half2_rn(f1W[t]);
        w[t] = __builtin_bit_cast(float, h);
    }
    if (t < 8) {
        __half2 h = __float2half2_rn(f1b[t]);
        w[72 + t] = __builtin_bit_cast(float, h);
    }
    if (t < 64) w[80 + t]   = f20W[t];
    if (t < 8)  w[144 + t]  = f20b[t] + fast_softplus(f2tb[t]);  // bias pre-fold
    if (t < 8)  w[152 + t]  = fast_softplus(f2tW[t]);
    if (t < 8)  w[160 + t]  = fast_softplus(f2tb[t]);
    if (t < 64) w[168 + t]  = fast_softplus(f21W[t]);
    if (t < 8)  w[232 + t]  = fast_softplus(f21b[t]);
    if (t < 8)  w[240 + t]  = fast_softplus(f22W[t]);
    if (t == 0) w[248]      = fast_softplus(f22b[0]);
}

// f32 f2 head (high-gain layers stay f32; tanh on trans pipe): flow[8] -> hazard
__device__ __forceinline__ float f2_head(const float* __restrict__ w,
                                         const float fl[8], float tv) {
    float h[8];
    #pragma unroll
    for (int o = 0; o < 8; ++o) {
        float acc = fmaf(tv, uload(w + 152 + o), uload(w + 144 + o));
        #pragma unroll
        for (int k = 0; k < 8; ++k) acc = fmaf(uload(w + 80 + o * 8 + k), fl[k], acc);
        h[o] = fast_tanh(acc);
    }
    float g[8];
    #pragma unroll
    for (int o = 0; o < 8; ++o) {
        float acc = uload(w + 232 + o);
        #pragma unroll
        for (int k = 0; k < 8; ++k) acc = fmaf(uload(w + 168 + o * 8 + k), h[k], acc);
        g[o] = fast_tanh(acc);
    }
    float z = uload(w + 248);
    #pragma unroll
    for (int k = 0; k < 8; ++k) z = fmaf(uload(w + 240 + k), g[k], z);
    return fast_softplus(z);
}

// ---------- main kernel: one thread per TWO rows, f1 recurrence in v_pk_*_f16 ----------
__global__ void __launch_bounds__(256) haz_kernel(
    const float* __restrict__ Y,
    const float* __restrict__ tau,
    const float* __restrict__ w,
    float* __restrict__ out,
    int npairs, int n)
{
    int i = blockIdx.x * blockDim.x + threadIdx.x;
    if (i >= npairs) return;
    int r0 = 2 * i;
    bool has1 = (r0 + 1) < n;
    int r1 = has1 ? r0 + 1 : r0;

    // tau prefetch: coalesced 8B load issued first so its latency hides
    // under the f1 recurrence.
    float tv0, tv1;
    if (has1) {
        float2 t2 = ((const float2*)tau)[i];
        tv0 = t2.x; tv1 = t2.y;
    } else {
        tv0 = tau[r0]; tv1 = tv0;          // avoid 4B OOB read on odd tail
    }

    union R { float4 v[4]; float s[16]; };
    R A, B;
    const float4* ya = (const float4*)(Y + (size_t)r0 * 16);
    const float4* yb = (const float4*)(Y + (size_t)r1 * 16);
    A.v[0] = ya[0]; A.v[1] = ya[1]; A.v[2] = ya[2]; A.v[3] = ya[3];
    B.v[0] = yb[0]; B.v[1] = yb[1]; B.v[2] = yb[2]; B.v[3] = yb[3];

    // pk_tanh coefficients: dup-packed f16 pairs, pinned once into VGPRs.
    TanhC tc;
    tc.a1 = 0x2FC22FC2u;   // 0.12121212
    tc.a2 = 0x18231823u;   // 0.00202020
    tc.b1 = 0x37463746u;   // 0.45454545
    tc.b2 = 0x252C252Cu;   // 0.02020202
    tc.b3 = 0x064E064Eu;   // 9.62001e-5
    tc.one = 0x3C003C00u;  // 1.0

    // yd[t] = log(diff+0.1) computed in f32 (trans pipe), packed (rowA, rowB)
    __half2 yd[11];
    #pragma unroll
    for (int j = 0; j < 11; ++j) {
        float da = fast_ln(A.s[4 + j] - A.s[3 + j] + 0.1f);
        float db = fast_ln(B.s[4 + j] - B.s[3 + j] + 0.1f);
        yd[j] = __halves2half2(__float2half(da), __float2half(db));
    }

    // f1 weights: dup-packed half2 bits pinned to SGPRs
    unsigned int Wk[72], Bk[8];
    #pragma unroll
    for (int k = 0; k < 72; ++k) Wk[k] = uload_bits(w + k);
    #pragma unroll
    for (int k = 0; k < 8; ++k)  Bk[k] = uload_bits(w + 72 + k);

    // recurrent f1: 11 steps of tanh(Linear(9->8)), both rows packed in half2
    __half2 flow[8];
    #pragma unroll
    for (int k = 0; k < 8; ++k) flow[k] = __float2half2_rn(0.0f);

    #pragma unroll
    for (int t = 0; t < 11; ++t) {
        __half2 nf[8];
        #pragma unroll
        for (int o = 0; o < 8; ++o) {
            __half2 acc = __builtin_bit_cast(__half2, Bk[o]);
            #pragma unroll
            for (int k = 0; k < 8; ++k)
                acc = __hfma2(__builtin_bit_cast(__half2, Wk[o * 9 + k]), flow[k], acc);
            acc = __hfma2(__builtin_bit_cast(__half2, Wk[o * 9 + 8]), yd[t], acc);
            nf[o] = pk_tanh(acc, tc);
        }
        #pragma unroll
        for (int o = 0; o < 8; ++o) flow[o] = nf[o];
    }

    // unpack to f32; run the high-gain f2 head per row in f32
    float flA[8], flB[8];
    #pragma unroll
    for (int k = 0; k < 8; ++k) {
        flA[k] = __low2float(flow[k]);
        flB[k] = __high2float(flow[k]);
    }

    float o0 = f2_head(w, flA, tv0);
    float o1 = f2_head(w, flB, tv1);

    if (has1) {
        ((float2*)out)[i] = make_float2(o0, o1);
    } else {
        out[r0] = o0;
    }
}

extern "C" void kernel_launch(void* const* d_in, const int* in_sizes, int n_in,
                              void* d_out, int out_size, void* d_ws, size_t ws_size,
                              hipStream_t stream)
{
    const float* Y   = (const float*)d_in[0];
    const float* tau = (const float*)d_in[1];
    float* w = (float*)d_ws;
    float* out = (float*)d_out;
    int n = in_sizes[1];
    int npairs = (n + 1) / 2;

    prep_kernel<<<1, 128, 0, stream>>>(
        (const float*)d_in[2],  (const float*)d_in[3],
        (const float*)d_in[4],  (const float*)d_in[5],
        (const float*)d_in[6],  (const float*)d_in[7],
        (const float*)d_in[8],  (const float*)d_in[9],
        (const float*)d_in[10], (const float*)d_in[11],
        w);

    haz_kernel<<<(npairs + 255) / 256, 256, 0, stream>>>(Y, tau, w, out, npairs, n);
}

// Round 4
// 410.811 us; speedup vs baseline: 1.0488x; 1.0464x over previous
//
#include <hip/hip_runtime.h>
#include <hip/hip_fp16.h>
#include <stdint.h>

#define LOG2E 1.4426950408889634f
#define LN2   0.6931471805599453f

typedef unsigned long long u64;

// ---------- scalar trans helpers ----------
__device__ __forceinline__ float fast_softplus(float x) {
    float ax = fabsf(x);
    float t = LN2 * __builtin_amdgcn_logf(1.0f + __builtin_amdgcn_exp2f(-LOG2E * ax));
    return fmaxf(x, 0.0f) + t;
}
__device__ __forceinline__ float fast_ln(float x) {
    return LN2 * __builtin_amdgcn_logf(x);
}
__device__ __forceinline__ float fast_tanh(float x) {
    // tanh(x) = 1 - 2/(exp(2x)+1); trans-pipe version (used only in f2: 16/row)
    float e = __builtin_amdgcn_exp2f(x * (2.0f * LOG2E));
    return 1.0f - 2.0f * __builtin_amdgcn_rcpf(e + 1.0f);
}

// uniform load pinned to SGPR (returns raw bits) — used only for f1 weights
__device__ __forceinline__ unsigned int uload_bits(const float* __restrict__ p) {
    return (unsigned int)__builtin_amdgcn_readfirstlane(__float_as_int(*p));
}

// ---------- packed f32 FMA: dup-packed weight pair in SGPRs (s_load'ed),
// fl/acc in VGPR pairs. All sources are legal 64-bit operands; exactly one
// SGPR source per instruction. ----------
__device__ __forceinline__ u64 uload64(const float2* __restrict__ p) {
    return __builtin_bit_cast(u64, *p);     // uniform addr -> s_load_dwordx2
}
__device__ __forceinline__ float2 pk_fma_s(u64 wpair, float2 x, float2 acc) {
    float2 d;
    asm("v_pk_fma_f32 %0, %1, %2, %3"
        : "=v"(d) : "s"(wpair), "v"(x), "v"(acc));
    return d;
}
__device__ __forceinline__ float2 tanh2(float2 x) {
    return make_float2(fast_tanh(x.x), fast_tanh(x.y));
}

// ---------- pk_tanh constants, held in VGPRs for the whole kernel ----------
struct TanhC {
    unsigned a1, a2, b1, b2, b3, one;
};

// ---------- packed f16 tanh: 11 VOP3P instructions via inline asm ----------
__device__ __forceinline__ __half2 pk_tanh(__half2 xh, const TanhC& c) {
    unsigned x = __builtin_bit_cast(unsigned, xh);
    unsigned o, t, n, d, r, e;
    asm("v_pk_mul_f16 %1, %6, %6\n\t"                                   // t = x*x
        "v_pk_fma_f16 %2, %1, %8, %7\n\t"                               // n = a2*t + a1
        "v_pk_fma_f16 %2, %1, %2, %12\n\t"                              // n = n*t + 1
        "v_pk_mul_f16 %2, %2, %6\n\t"                                   // n *= x
        "v_pk_fma_f16 %3, %1, %11, %10\n\t"                             // d = b3*t + b2
        "v_pk_fma_f16 %3, %1, %3, %9\n\t"                               // d = d*t + b1
        "v_pk_fma_f16 %3, %1, %3, %12\n\t"                              // d = d*t + 1
        "v_sub_u32    %4, 0x77997799, %3\n\t"                           // magic rcp seed
        "v_pk_fma_f16 %5, %4, %3, %12 neg_lo:[0,1,0] neg_hi:[0,1,0]\n\t"// e = 1 - r*d
        "v_pk_fma_f16 %4, %4, %5, %4\n\t"                               // r = r*e + r
        "v_pk_mul_f16 %0, %2, %4"                                       // o = n*r
        : "=v"(o), "=&v"(t), "=&v"(n), "=&v"(d), "=&v"(r), "=&v"(e)
        : "v"(x), "v"(c.a1), "v"(c.a2), "v"(c.b1), "v"(c.b2), "v"(c.b3),
          "v"(c.one));
    return __builtin_bit_cast(__half2, o);
}

// ---------- weight prep ----------
// ws layout (floats):
//   [0..71]    f1_W dup-packed half2      [72..79]   f1_b dup-packed half2
//   [80..248]  legacy scalar f2 weights (unused by haz_kernel now)
//   [256..]    f2 weights dup-packed as float2 {w,w} pairs, pair-index space:
//     pairs [0..63]    f2_0_W          pairs [64..71]   f2_0_b + sp(f2tau_b)
//     pairs [72..79]   sp(f2tau_W)     pairs [80..143]  sp(f2_1_W)
//     pairs [144..151] sp(f2_1_b)      pairs [152..159] sp(f2_2_W)
//     pair  [160]      sp(f2_2_b)
__global__ void prep_kernel(
    const float* __restrict__ f1W,  const float* __restrict__ f1b,
    const float* __restrict__ f2tW, const float* __restrict__ f2tb,
    const float* __restrict__ f20W, const float* __restrict__ f20b,
    const float* __restrict__ f21W, const float* __restrict__ f21b,
    const float* __restrict__ f22W, const float* __restrict__ f22b,
    float* __restrict__ w)
{
    int t = threadIdx.x;
    float2* w2 = (float2*)(w + 256);
    if (t < 72) {
        __half2 h = __float2half2_rn(f1W[t]);
        w[t] = __builtin_bit_cast(float, h);
    }
    if (t < 8) {
        __half2 h = __float2half2_rn(f1b[t]);
        w[72 + t] = __builtin_bit_cast(float, h);
    }
    if (t < 64) {
        w2[t] = make_float2(f20W[t], f20W[t]);
        float v = fast_softplus(f21W[t]);
        w2[80 + t] = make_float2(v, v);
    }
    if (t < 8) {
        float b0 = f20b[t] + fast_softplus(f2tb[t]);   // bias pre-fold
        w2[64 + t] = make_float2(b0, b0);
        float tw = fast_softplus(f2tW[t]);
        w2[72 + t] = make_float2(tw, tw);
        float b1 = fast_softplus(f21b[t]);
        w2[144 + t] = make_float2(b1, b1);
        float v2 = fast_softplus(f22W[t]);
        w2[152 + t] = make_float2(v2, v2);
    }
    if (t == 0) {
        float v = fast_softplus(f22b[0]);
        w2[160] = make_float2(v, v);
    }
}

// ---------- packed f2 head: BOTH rows in one pass via v_pk_fma_f32 ----------
// Full f32 precision; weights via s_load (SMEM pipe, zero VALU); tanh on trans.
__device__ __forceinline__ float2 f2_head2(const float2* __restrict__ w2,
                                           const float2 fl2[8], float2 tv2) {
    float2 h2[8];
    #pragma unroll
    for (int o = 0; o < 8; ++o) {
        float2 acc = w2[64 + o];                             // folded bias pair
        acc = pk_fma_s(uload64(w2 + 72 + o), tv2, acc);      // + tau * sp(tauW)
        #pragma unroll
        for (int k = 0; k < 8; ++k)
            acc = pk_fma_s(uload64(w2 + o * 8 + k), fl2[k], acc);
        h2[o] = tanh2(acc);
    }
    float2 g2[8];
    #pragma unroll
    for (int o = 0; o < 8; ++o) {
        float2 acc = w2[144 + o];
        #pragma unroll
        for (int k = 0; k < 8; ++k)
            acc = pk_fma_s(uload64(w2 + 80 + o * 8 + k), h2[k], acc);
        g2[o] = tanh2(acc);
    }
    float2 z2 = w2[160];
    #pragma unroll
    for (int k = 0; k < 8; ++k)
        z2 = pk_fma_s(uload64(w2 + 152 + k), g2[k], z2);
    return make_float2(fast_softplus(z2.x), fast_softplus(z2.y));
}

// ---------- main kernel: one thread per TWO rows, f1 recurrence in v_pk_*_f16 ----------
__global__ void __launch_bounds__(256) haz_kernel(
    const float* __restrict__ Y,
    const float* __restrict__ tau,
    const float* __restrict__ w,
    float* __restrict__ out,
    int npairs, int n)
{
    int i = blockIdx.x * blockDim.x + threadIdx.x;
    if (i >= npairs) return;
    int r0 = 2 * i;
    bool has1 = (r0 + 1) < n;
    int r1 = has1 ? r0 + 1 : r0;

    // tau prefetch: coalesced 8B load issued first so its latency hides
    // under the f1 recurrence.
    float2 tv2;
    if (has1) {
        tv2 = ((const float2*)tau)[i];
    } else {
        tv2.x = tau[r0]; tv2.y = tv2.x;    // avoid 4B OOB read on odd tail
    }

    union R { float4 v[4]; float s[16]; };
    R A, B;
    const float4* ya = (const float4*)(Y + (size_t)r0 * 16);
    const float4* yb = (const float4*)(Y + (size_t)r1 * 16);
    A.v[0] = ya[0]; A.v[1] = ya[1]; A.v[2] = ya[2]; A.v[3] = ya[3];
    B.v[0] = yb[0]; B.v[1] = yb[1]; B.v[2] = yb[2]; B.v[3] = yb[3];

    // pk_tanh coefficients: dup-packed f16 pairs, pinned once into VGPRs.
    TanhC tc;
    tc.a1 = 0x2FC22FC2u;   // 0.12121212
    tc.a2 = 0x18231823u;   // 0.00202020
    tc.b1 = 0x37463746u;   // 0.45454545
    tc.b2 = 0x252C252Cu;   // 0.02020202
    tc.b3 = 0x064E064Eu;   // 9.62001e-5
    tc.one = 0x3C003C00u;  // 1.0

    // yd[t] = log(diff+0.1) computed in f32 (trans pipe), packed (rowA, rowB)
    __half2 yd[11];
    #pragma unroll
    for (int j = 0; j < 11; ++j) {
        float da = fast_ln(A.s[4 + j] - A.s[3 + j] + 0.1f);
        float db = fast_ln(B.s[4 + j] - B.s[3 + j] + 0.1f);
        yd[j] = __builtin_bit_cast(__half2, __builtin_amdgcn_cvt_pkrtz(da, db));
    }

    // f1 weights: dup-packed half2 bits pinned to SGPRs
    unsigned int Wk[72], Bk[8];
    #pragma unroll
    for (int k = 0; k < 72; ++k) Wk[k] = uload_bits(w + k);
    #pragma unroll
    for (int k = 0; k < 8; ++k)  Bk[k] = uload_bits(w + 72 + k);

    // recurrent f1: 11 steps of tanh(Linear(9->8)), both rows packed in half2
    __half2 flow[8];
    #pragma unroll
    for (int k = 0; k < 8; ++k) flow[k] = __float2half2_rn(0.0f);

    #pragma unroll
    for (int t = 0; t < 11; ++t) {
        __half2 nf[8];
        #pragma unroll
        for (int o = 0; o < 8; ++o) {
            __half2 acc = __builtin_bit_cast(__half2, Bk[o]);
            #pragma unroll
            for (int k = 0; k < 8; ++k)
                acc = __hfma2(__builtin_bit_cast(__half2, Wk[o * 9 + k]), flow[k], acc);
            acc = __hfma2(__builtin_bit_cast(__half2, Wk[o * 9 + 8]), yd[t], acc);
            nf[o] = pk_tanh(acc, tc);
        }
        #pragma unroll
        for (int o = 0; o < 8; ++o) flow[o] = nf[o];
    }

    // unpack to f32 pairs (rowA in .x, rowB in .y); run packed f2 head
    float2 fl2[8];
    #pragma unroll
    for (int k = 0; k < 8; ++k) {
        fl2[k].x = __low2float(flow[k]);
        fl2[k].y = __high2float(flow[k]);
    }

    float2 o2 = f2_head2((const float2*)(w + 256), fl2, tv2);

    if (has1) {
        ((float2*)out)[i] = o2;
    } else {
        out[r0] = o2.x;
    }
}

extern "C" void kernel_launch(void* const* d_in, const int* in_sizes, int n_in,
                              void* d_out, int out_size, void* d_ws, size_t ws_size,
                              hipStream_t stream)
{
    const float* Y   = (const float*)d_in[0];
    const float* tau = (const float*)d_in[1];
    float* w = (float*)d_ws;
    float* out = (float*)d_out;
    int n = in_sizes[1];
    int npairs = (n + 1) / 2;

    prep_kernel<<<1, 128, 0, stream>>>(
        (const float*)d_in[2],  (const float*)d_in[3],
        (const float*)d_in[4],  (const float*)d_in[5],
        (const float*)d_in[6],  (const float*)d_in[7],
        (const float*)d_in[8],  (const float*)d_in[9],
        (const float*)d_in[10], (const float*)d_in[11],
        w);

    haz_kernel<<<(npairs + 255) / 256, 256, 0, stream>>>(Y, tau, w, out, npairs, n);
}